// Round 5
// baseline (1746.152 us; speedup 1.0000x reference)
//
#include <hip/hip_runtime.h>
#include <hip/hip_cooperative_groups.h>
#include <math.h>

namespace cg = cooperative_groups;

#define N_NODES 50000
#define N_EDGES 600000
#define HID 128
#define N_GRAPHS 64
#define BCAP 32        // bucket capacity; overflow folded into agg rare path
#define OVF_CAP 4096
#define PCHUNK 8
#define LDSP 136       // padded LDS row stride (bf16): 272B = 17*16B, 16B-aligned rows
#define MLPB ((N_NODES + 31) / 32)

typedef __attribute__((ext_vector_type(8))) short short8;
typedef __attribute__((ext_vector_type(4))) float floatx4;

__device__ __forceinline__ float softplus_f(float v) {
    return fmaxf(v, 0.0f) + __logf(1.0f + __expf(-fabsf(v)));
}
__device__ __forceinline__ unsigned short f2bf(float f) {
    unsigned u = __float_as_uint(f);
    u = (u + 0x7FFFu + ((u >> 16) & 1u)) >> 16;   // RNE; inputs finite
    return (unsigned short)u;
}
__device__ __forceinline__ float bflo(unsigned u) { return __uint_as_float(u << 16); }
__device__ __forceinline__ float bfhi(unsigned u) { return __uint_as_float(u & 0xFFFF0000u); }
__device__ __forceinline__ uint2 bfpack4(float4 v) {
    uint2 o;
    o.x = (unsigned)f2bf(v.x) | ((unsigned)f2bf(v.y) << 16);
    o.y = (unsigned)f2bf(v.z) | ((unsigned)f2bf(v.w) << 16);
    return o;
}

struct Params {
    const float* node_attr;
    const float* edge_attr;
    const int*   ei;
    const int*   batch;
    const float* W1; const float* B1;
    const float* W2; const float* B2;
    float* gout; float* nodeout;
    unsigned short* nab; unsigned short* bufA; unsigned short* bufB;
    int* cnt; int4* ovf; int2* bkt;
    unsigned short* pw;
    int* startb; float* part;
};

// ---- round-0 agg body, verbatim (wave/node, half-wave/edge) ----
__device__ __forceinline__ void agg_node(int n, int lane,
        const unsigned short* __restrict__ xb, const float* __restrict__ edge_attr,
        const int* __restrict__ cnt, const int2* __restrict__ bkt,
        const int4* __restrict__ ovf, unsigned short* __restrict__ outb) {
    if (n >= N_NODES) return;
    n = __builtin_amdgcn_readfirstlane(n);
    int h = lane >> 5;          // which edge of a pair this half-wave handles
    int l = lane & 31;          // float4 index in the 128-feat row
    int ctot = cnt[n];
    int c = ctot < BCAP ? ctot : BCAP;
    const int2* bk = bkt + (size_t)n * BCAP;
    float4 acc = make_float4(0.f, 0.f, 0.f, 0.f);
    int s = 0;
    for (; s + 4 <= c; s += 4) {
        int2 pA = bk[s + h];
        int2 pB = bk[s + 2 + h];
        float4 eA = *(const float4*)(edge_attr + (size_t)pA.x * HID + l * 4);
        uint2  xA = *(const uint2*)(xb + (size_t)pA.y * HID + l * 4);
        float4 eB = *(const float4*)(edge_attr + (size_t)pB.x * HID + l * 4);
        uint2  xB = *(const uint2*)(xb + (size_t)pB.y * HID + l * 4);
        acc.x += softplus_f(eA.x + bflo(xA.x)) + softplus_f(eB.x + bflo(xB.x));
        acc.y += softplus_f(eA.y + bfhi(xA.x)) + softplus_f(eB.y + bfhi(xB.x));
        acc.z += softplus_f(eA.z + bflo(xA.y)) + softplus_f(eB.z + bflo(xB.y));
        acc.w += softplus_f(eA.w + bfhi(xA.y)) + softplus_f(eB.w + bfhi(xB.y));
    }
    if (s + 2 <= c) {
        int2 p = bk[s + h];
        float4 ev = *(const float4*)(edge_attr + (size_t)p.x * HID + l * 4);
        uint2  xv = *(const uint2*)(xb + (size_t)p.y * HID + l * 4);
        acc.x += softplus_f(ev.x + bflo(xv.x));
        acc.y += softplus_f(ev.y + bfhi(xv.x));
        acc.z += softplus_f(ev.z + bflo(xv.y));
        acc.w += softplus_f(ev.w + bfhi(xv.y));
        s += 2;
    }
    if (s < c && h == 0) {
        int2 p = bk[s];
        float4 ev = *(const float4*)(edge_attr + (size_t)p.x * HID + l * 4);
        uint2  xv = *(const uint2*)(xb + (size_t)p.y * HID + l * 4);
        acc.x += softplus_f(ev.x + bflo(xv.x));
        acc.y += softplus_f(ev.y + bfhi(xv.x));
        acc.z += softplus_f(ev.z + bflo(xv.y));
        acc.w += softplus_f(ev.w + bfhi(xv.y));
    }
    if (ctot > BCAP) {          // rare: scan overflow list for this dst
        int k = cnt[N_NODES]; if (k > OVF_CAP) k = OVF_CAP;
        for (int i = 0; i < k; i++) {
            int4 t = ovf[i];
            if (t.z == n && h == 0) {
                float4 ev = *(const float4*)(edge_attr + (size_t)t.x * HID + l * 4);
                uint2  xv = *(const uint2*)(xb + (size_t)t.y * HID + l * 4);
                acc.x += softplus_f(ev.x + bflo(xv.x));
                acc.y += softplus_f(ev.y + bfhi(xv.x));
                acc.z += softplus_f(ev.z + bflo(xv.y));
                acc.w += softplus_f(ev.w + bfhi(xv.y));
            }
        }
    }
    acc.x += __shfl(acc.x, l + 32);
    acc.y += __shfl(acc.y, l + 32);
    acc.z += __shfl(acc.z, l + 32);
    acc.w += __shfl(acc.w, l + 32);
    if (h == 0) {
        uint2 xn = *(const uint2*)(xb + (size_t)n * HID + l * 4);
        acc.x += bflo(xn.x); acc.y += bfhi(xn.x);
        acc.z += bflo(xn.y); acc.w += bfhi(xn.y);
        unsigned o0 = (unsigned)f2bf(acc.x) | ((unsigned)f2bf(acc.y) << 16);
        unsigned o1 = (unsigned)f2bf(acc.z) | ((unsigned)f2bf(acc.w) << 16);
        *(uint2*)(outb + (size_t)n * HID + l * 4) = make_uint2(o0, o1);
    }
}

// ---- round-0 mlp body, verbatim (blockIdx.x -> bx, threadIdx.x -> tid) ----
__device__ __forceinline__ void mlp_tile(int bx, int tid,
        unsigned short (&hl)[2][16][LDSP],
        const unsigned short* __restrict__ A,
        const unsigned short* __restrict__ pw1, const unsigned short* __restrict__ pw2,
        const float* __restrict__ b1, const float* __restrict__ b2,
        void* __restrict__ outp, int final_layer) {
    int wave = tid >> 6, lane = tid & 63;
    int rt = wave >> 1, ch = wave & 1;
    int m = lane & 15, q = lane >> 4;
    int r0 = bx * 32 + rt * 16;
    int row = r0 + m;
    bool rv = row < N_NODES;
    short8 zf = {0, 0, 0, 0, 0, 0, 0, 0};
    floatx4 zero = {0.f, 0.f, 0.f, 0.f};
    floatx4 acc[4];
    #pragma unroll
    for (int t = 0; t < 4; t++) acc[t] = zero;
    const short8* ar = (const short8*)(A + (size_t)row * HID + q * 8);
    const short8* w1 = (const short8*)pw1;
    #pragma unroll
    for (int kt = 0; kt < 4; kt++) {
        short8 af = rv ? ar[kt * 4] : zf;   // A[row][kt*32+q*8 ..+8], direct bf16
        const short8* wp = w1 + (size_t)(kt * 8 + ch * 4) * 64 + lane;
        #pragma unroll
        for (int t = 0; t < 4; t++)
            acc[t] = __builtin_amdgcn_mfma_f32_16x16x32_bf16(af, wp[t * 64], acc[t], 0, 0, 0);
    }
    // epilogue 1: h = softplus(acc + b1) -> bf16 -> LDS (C-layout -> A-layout)
    #pragma unroll
    for (int t = 0; t < 4; t++) {
        int col = ch * 64 + t * 16 + m;
        float bb = b1[col];
        #pragma unroll
        for (int i = 0; i < 4; i++)
            hl[rt][q * 4 + i][col] = f2bf(softplus_f(acc[t][i] + bb));
    }
    __syncthreads();
    #pragma unroll
    for (int t = 0; t < 4; t++) acc[t] = zero;
    const short8* w2 = (const short8*)pw2;
    #pragma unroll
    for (int kt = 0; kt < 4; kt++) {
        short8 af = *(const short8*)&hl[rt][m][kt * 32 + q * 8];
        const short8* wp = w2 + (size_t)(kt * 8 + ch * 4) * 64 + lane;
        #pragma unroll
        for (int t = 0; t < 4; t++)
            acc[t] = __builtin_amdgcn_mfma_f32_16x16x32_bf16(af, wp[t * 64], acc[t], 0, 0, 0);
    }
    if (final_layer) {
        float* out = (float*)outp;
        #pragma unroll
        for (int t = 0; t < 4; t++) {
            int col = ch * 64 + t * 16 + m;
            float bb = b2[col];
            #pragma unroll
            for (int i = 0; i < 4; i++) {
                int r = r0 + q * 4 + i;
                if (r < N_NODES) out[(size_t)r * HID + col] = acc[t][i] + bb;
            }
        }
    } else {
        __syncthreads();    // all GEMM2 LDS reads done before overwrite
        #pragma unroll
        for (int t = 0; t < 4; t++) {
            int col = ch * 64 + t * 16 + m;
            float bb = b2[col];
            #pragma unroll
            for (int i = 0; i < 4; i++)
                hl[rt][q * 4 + i][col] = f2bf(softplus_f(acc[t][i] + bb));
        }
        __syncthreads();
        // coalesced copy-out: thread -> (row = tid>>3, 16-col segment)
        unsigned short* outb = (unsigned short*)outp;
        int orow = tid >> 3, cseg = (tid & 7) * 16;
        int gr = bx * 32 + orow;
        if (gr < N_NODES) {
            uint4 v0 = *(const uint4*)&hl[orow >> 4][orow & 15][cseg];
            uint4 v1 = *(const uint4*)&hl[orow >> 4][orow & 15][cseg + 8];
            *(uint4*)(outb + (size_t)gr * HID + cseg) = v0;
            *(uint4*)(outb + (size_t)gr * HID + cseg + 8) = v1;
        }
    }
}

// ==== single cooperative kernel: whole forward pass, grid.sync between phases ====
__global__ void __launch_bounds__(256, 6) gin_all(Params p) {
    cg::grid_group grid = cg::this_grid();
    __shared__ __align__(16) unsigned short hl[2][16][LDSP];
    const int tid  = threadIdx.x;
    const int G    = gridDim.x;
    const int gtid = blockIdx.x * 256 + tid;
    const int NT   = G * 256;

    // ---- phase 0: zero bucket counters ----
    for (int i = gtid; i < N_NODES + 1; i += NT) p.cnt[i] = 0;
    grid.sync();

    // ---- phase 1: build buckets + pack_x + pack_w + find_bounds ----
    for (int e = gtid; e < N_EDGES; e += NT) {
        int src = p.ei[e];
        int dst = p.ei[N_EDGES + e];
        int slot = atomicAdd(&p.cnt[dst], 1);
        if (slot < BCAP) {
            p.bkt[(size_t)dst * BCAP + slot] = make_int2(e, src);
        } else {
            int k = atomicAdd(&p.cnt[N_NODES], 1);
            if (k < OVF_CAP) p.ovf[k] = make_int4(e, src, dst, 0);
        }
    }
    for (int t = gtid; t < (int)((size_t)N_NODES * HID / 4); t += NT) {
        float4 v = *(const float4*)(p.node_attr + (size_t)t * 4);
        *(uint2*)(p.nab + (size_t)t * 4) = bfpack4(v);
    }
    for (int t = gtid; t < 6 * 32 * 64; t += NT) {
        int lane = t & 63;
        int tile = (t >> 6) & 31;
        int mat = t >> 11;                       // 0..5 = layer*2 + which
        int kt = tile >> 3, nt = tile & 7;
        const float* W = (mat & 1) ? p.W2 : p.W1;
        W += (size_t)(mat >> 1) * HID * HID;
        int n = nt * 16 + (lane & 15);
        int kbase = kt * 32 + (lane >> 4) * 8;
        short8 v;
        #pragma unroll
        for (int j = 0; j < 8; j++) v[j] = (short)f2bf(W[(size_t)n * HID + kbase + j]);
        *((short8*)(p.pw + (size_t)t * 8)) = v;
    }
    for (int n = gtid; n < N_NODES; n += NT) {
        int bn = p.batch[n];
        int bp = (n == 0) ? -1 : p.batch[n - 1];
        for (int g = bp + 1; g <= bn; g++) p.startb[g] = n;
        if (n == N_NODES - 1)
            for (int g = bn + 1; g <= N_GRAPHS; g++) p.startb[g] = N_NODES;
    }
    grid.sync();

    // ---- phases 2..7: three (agg -> mlp) layers ----
    const unsigned short* xcur = p.nab;
    const int wv0 = blockIdx.x * 4 + (tid >> 6);
    const int lane = tid & 63;
    for (int layer = 0; layer < 3; layer++) {
        for (int n = wv0; n < N_NODES; n += G * 4)
            agg_node(n, lane, xcur, p.edge_attr, p.cnt, p.bkt, p.ovf, p.bufA);
        grid.sync();

        const unsigned short* pw1 = p.pw + (size_t)(layer * 2) * 16384;
        const unsigned short* pw2 = p.pw + (size_t)(layer * 2 + 1) * 16384;
        const float* b1 = p.B1 + (size_t)layer * HID;
        const float* b2 = p.B2 + (size_t)layer * HID;
        int fin = (layer == 2);
        void* outp = fin ? (void*)p.nodeout : (void*)p.bufB;
        for (int vb = blockIdx.x; vb < MLPB; vb += G) {
            __syncthreads();    // previous iteration's hl reads done
            mlp_tile(vb, tid, hl, p.bufA, pw1, pw2, b1, b2, outp, fin);
        }
        grid.sync();
        xcur = p.bufB;
    }

    // ---- phase 8: pool partials (graph g, chunk c); 128 threads per virtual block ----
    {
        int sub = tid >> 7, j = tid & 127;
        for (int vb = blockIdx.x * 2 + sub; vb < N_GRAPHS * PCHUNK; vb += G * 2) {
            int g = vb >> 3, c = vb & (PCHUNK - 1);
            int s = p.startb[g], e = p.startb[g + 1];
            int len = e - s;
            int b0 = s + (len * c) / PCHUNK;
            int b1i = s + (len * (c + 1)) / PCHUNK;
            float acc = 0.f;
            for (int n = b0; n < b1i; n++) acc += p.nodeout[(size_t)n * HID + j];
            p.part[(size_t)vb * HID + j] = acc;
        }
    }
    grid.sync();

    // ---- phase 9: pool final ----
    {
        int sub = tid >> 7, j = tid & 127;
        for (int g = blockIdx.x * 2 + sub; g < N_GRAPHS; g += G * 2) {
            float acc = 0.f;
            #pragma unroll
            for (int c = 0; c < PCHUNK; c++)
                acc += p.part[(size_t)(g * PCHUNK + c) * HID + j];
            p.gout[(size_t)g * HID + j] = acc;
        }
    }
}

extern "C" void kernel_launch(void* const* d_in, const int* in_sizes, int n_in,
                              void* d_out, int out_size, void* d_ws, size_t ws_size,
                              hipStream_t stream) {
    Params p;
    p.node_attr = (const float*)d_in[0];
    p.edge_attr = (const float*)d_in[1];
    p.ei        = (const int*)d_in[2];
    p.batch     = (const int*)d_in[3];
    p.W1        = (const float*)d_in[4];
    p.B1        = (const float*)d_in[5];
    p.W2        = (const float*)d_in[6];
    p.B2        = (const float*)d_in[7];

    p.gout    = (float*)d_out;                    // [64,128]
    p.nodeout = (float*)d_out + N_GRAPHS * HID;   // [50000,128]

    const size_t NH = (size_t)N_NODES * HID;
    p.nab  = (unsigned short*)d_ws;               // bf16 node_attr
    p.bufA = p.nab + NH;                          // bf16 agg out (MLP A)
    p.bufB = p.bufA + NH;                         // bf16 x between layers
    p.cnt  = (int*)(p.bufB + NH);                 // [0..49999]=deg, [50000]=ovf cnt (+pad)
    p.ovf  = (int4*)(p.cnt + 50004);              // OVF_CAP (16B aligned)
    p.bkt  = (int2*)(p.ovf + OVF_CAP);            // 50000*BCAP
    p.pw   = (unsigned short*)(p.bkt + (size_t)N_NODES * BCAP);  // 6*16384
    p.startb = (int*)(p.pw + 6 * 16384);          // 65 (+pad)
    p.part = (float*)(p.startb + 68);             // 64*PCHUNK*128

    static int maxb = -1;
    if (maxb < 0) {
        int mb = 0;
        hipError_t err = hipOccupancyMaxActiveBlocksPerMultiprocessor(
                &mb, (const void*)gin_all, 256, 0);
        maxb = (err == hipSuccess && mb > 0) ? mb : 4;
    }
    int G = maxb * 256;            // 256 CUs on MI355X
    if (G > 1536) G = 1536;

    void* kp[1] = { (void*)&p };
    hipLaunchCooperativeKernel((const void*)gin_all, dim3(G), dim3(256), kp, 0, stream);
}